// Round 1
// baseline (172.457 us; speedup 1.0000x reference)
//
#include <hip/hip_runtime.h>
#include <math.h>

#define DD   128
#define DI   170
#define BB   4096
#define NNEG 5
#define ROWS 16
#define NBLK (BB / ROWS)   // 256 blocks
#define SQRT_D 11.3137084989847603904f   // sqrt(128)

__device__ __forceinline__ float wave_bcast_sum(float v) {
#pragma unroll
    for (int m = 1; m < 64; m <<= 1) v += __shfl_xor(v, m, 64);
    return v;
}

// Kernel 1: inverse L2 norms for W_hidden rows, W_gate rows, W_ff_out columns.
// Also zeroes the output accumulator (d_out is poisoned before every call).
__global__ __launch_bounds__(256) void norms_kernel(
    const float* __restrict__ W_hidden,
    const float* __restrict__ W_gate,
    const float* __restrict__ W_ff_out,
    float* __restrict__ inv_h,
    float* __restrict__ inv_g,
    float* __restrict__ inv_f,
    float* __restrict__ out)
{
    if (blockIdx.x == 0 && threadIdx.x == 0) out[0] = 0.0f;
    const int wave = threadIdx.x >> 6;
    const int lane = threadIdx.x & 63;
    const int v = blockIdx.x * 4 + wave;          // 0 .. 511 (510 used)
    if (v >= 3 * DI) return;
    float s;
    if (v < 2 * DI) {
        const float* W = (v < DI) ? W_hidden : W_gate;
        const int row = (v < DI) ? v : v - DI;
        float2 p = ((const float2*)(W + (long)row * DD))[lane];
        s = p.x * p.x + p.y * p.y;
    } else {
        const int c = v - 2 * DI;                 // column of W_ff_out (D x DI)
        float a = W_ff_out[(long)(2 * lane)     * DI + c];
        float b = W_ff_out[(long)(2 * lane + 1) * DI + c];
        s = a * a + b * b;
    }
    s = wave_bcast_sum(s);
    if (lane == 0) {
        float inv = rsqrtf(s);
        if (v < DI)            inv_h[v] = inv;
        else if (v < 2 * DI)   inv_g[v - DI] = inv;
        else                   inv_f[v - 2 * DI] = inv;
    }
}

__global__ __launch_bounds__(256) void main_kernel(
    const int*   __restrict__ input_ids,
    const int*   __restrict__ target_ids,
    const int*   __restrict__ neg_ids,
    const float* __restrict__ W_in,
    const float* __restrict__ W_out,
    const float* __restrict__ W_hidden,
    const float* __restrict__ W_gate,
    const float* __restrict__ W_ff_out,
    const float* __restrict__ hidden_scale,
    const float* __restrict__ gate_scale,
    const float* __restrict__ logit_scale,
    const float* __restrict__ inv_h,
    const float* __restrict__ inv_g,
    const float* __restrict__ inv_f,
    float* __restrict__ out)
{
    __shared__ float s_emb[ROWS][DD];        // 8 KB
    __shared__ float s_x[ROWS][DI + 2];      // 16 x 172 floats, rows 16B-aligned
    __shared__ float s_xout[ROWS][DD];       // 8 KB
    __shared__ float s_red[4];

    const int tid  = threadIdx.x;
    const int wave = tid >> 6;
    const int lane = tid & 63;
    const int b0   = blockIdx.x * ROWS;

    // ---- Phase 1: gather + l2-normalize input embeddings into LDS ----
#pragma unroll
    for (int k = 0; k < ROWS / 4; ++k) {
        const int r  = wave + 4 * k;
        const int id = input_ids[b0 + r];
        float2 p = ((const float2*)(W_in + (long)id * DD))[lane];
        float s  = wave_bcast_sum(p.x * p.x + p.y * p.y);
        float inv = rsqrtf(s);
        s_emb[r][2 * lane]     = p.x * inv;
        s_emb[r][2 * lane + 1] = p.y * inv;
    }
    __syncthreads();

    // ---- Phase 2: h = (emb @ l2n(Wh).T)*hs ; g = (emb @ l2n(Wg).T)*gs*sqrt(D)
    //      x = silu(g)*h ; fold in W_ff_out column inv-norm ----
    if (tid < DI) {
        const int i = tid;
        float ah[ROWS], ag[ROWS];
#pragma unroll
        for (int r = 0; r < ROWS; ++r) { ah[r] = 0.0f; ag[r] = 0.0f; }
        const float4* wh = (const float4*)(W_hidden + (long)i * DD);
        const float4* wg = (const float4*)(W_gate   + (long)i * DD);
        for (int d4 = 0; d4 < DD / 4; ++d4) {
            float4 h4 = wh[d4];
            float4 g4 = wg[d4];
#pragma unroll
            for (int r = 0; r < ROWS; ++r) {
                float4 e4 = ((const float4*)s_emb[r])[d4];   // same addr across lanes: broadcast
                ah[r] += e4.x * h4.x + e4.y * h4.y + e4.z * h4.z + e4.w * h4.w;
                ag[r] += e4.x * g4.x + e4.y * g4.y + e4.z * g4.z + e4.w * g4.w;
            }
        }
        const float hs = hidden_scale[i] * inv_h[i];
        const float gs = gate_scale[i]   * inv_g[i] * SQRT_D;
        const float fi = inv_f[i];
#pragma unroll
        for (int r = 0; r < ROWS; ++r) {
            float h = ah[r] * hs;
            float g = ag[r] * gs;
            float x = (g / (1.0f + __expf(-g))) * h;   // silu(g) * h
            s_x[r][i] = x * fi;
        }
    }
    __syncthreads();

    // ---- Phase 2b: xout[r][dd] = sum_i s_x[r][i] * W_ff_out[dd][i] ----
    {
        const int dd = tid & 127;
        const int r0 = tid >> 7;    // 0 or 1
        float acc[ROWS / 2];
#pragma unroll
        for (int k = 0; k < ROWS / 2; ++k) acc[k] = 0.0f;
        const float2* wrow = (const float2*)(W_ff_out + (long)dd * DI);  // 680B rows: 8B aligned
        for (int i2 = 0; i2 < DI / 2; ++i2) {
            float2 wf = wrow[i2];
#pragma unroll
            for (int k = 0; k < ROWS / 2; ++k) {
                const int r = r0 + 2 * k;
                float2 xv = *(const float2*)&s_x[r][2 * i2];   // broadcast across lanes
                acc[k] += xv.x * wf.x + xv.y * wf.y;
            }
        }
#pragma unroll
        for (int k = 0; k < ROWS / 2; ++k) s_xout[r0 + 2 * k][dd] = acc[k];
    }
    __syncthreads();

    // ---- Phase 3: gathered logits + negative-sampling loss ----
    float wacc = 0.0f;
    for (int t = wave; t < ROWS * (1 + NNEG); t += 4) {
        const int r  = t / (1 + NNEG);
        const int jj = t % (1 + NNEG);
        const int bidx = b0 + r;
        const int id = (jj == 0) ? target_ids[bidx] : neg_ids[bidx * NNEG + jj - 1];
        const float* wrow = W_out + (long)id * DD;
        float w0 = wrow[lane], w1 = wrow[64 + lane];
        float x0 = s_xout[r][lane], x1 = s_xout[r][64 + lane];
        float dot = w0 * x0 + w1 * x1;
        float ss  = w0 * w0 + w1 * w1;
#pragma unroll
        for (int m = 1; m < 64; m <<= 1) {
            dot += __shfl_xor(dot, m, 64);
            ss  += __shfl_xor(ss,  m, 64);
        }
        const float logit = dot * rsqrtf(ss) * logit_scale[id] * SQRT_D;
        const float z  = (jj == 0) ? logit : -logit;
        const float ls = fminf(z, 0.0f) - log1pf(__expf(-fabsf(z)));   // stable log_sigmoid
        wacc += (jj == 0) ? ls * (1.0f / BB) : ls * (1.0f / (BB * NNEG));
    }
    if (lane == 0) s_red[wave] = wacc;
    __syncthreads();
    if (tid == 0) {
        float tot = s_red[0] + s_red[1] + s_red[2] + s_red[3];
        atomicAdd(out, -tot);
    }
}

extern "C" void kernel_launch(void* const* d_in, const int* in_sizes, int n_in,
                              void* d_out, int out_size, void* d_ws, size_t ws_size,
                              hipStream_t stream) {
    (void)in_sizes; (void)n_in; (void)out_size; (void)ws_size;
    const int*   input_ids    = (const int*)  d_in[0];
    const int*   target_ids   = (const int*)  d_in[1];
    const int*   neg_ids      = (const int*)  d_in[2];
    const float* W_in         = (const float*)d_in[3];
    const float* W_out        = (const float*)d_in[4];
    const float* W_hidden     = (const float*)d_in[5];
    const float* W_gate       = (const float*)d_in[6];
    const float* W_ff_out     = (const float*)d_in[7];
    const float* hidden_scale = (const float*)d_in[8];
    const float* gate_scale   = (const float*)d_in[9];
    const float* logit_scale  = (const float*)d_in[10];
    float* out   = (float*)d_out;
    float* inv_h = (float*)d_ws;
    float* inv_g = inv_h + DI;
    float* inv_f = inv_g + DI;

    norms_kernel<<<128, 256, 0, stream>>>(W_hidden, W_gate, W_ff_out,
                                          inv_h, inv_g, inv_f, out);
    main_kernel<<<NBLK, 256, 0, stream>>>(input_ids, target_ids, neg_ids,
                                          W_in, W_out, W_hidden, W_gate, W_ff_out,
                                          hidden_scale, gate_scale, logit_scale,
                                          inv_h, inv_g, inv_f, out);
}